// Round 12
// baseline (529.883 us; speedup 1.0000x reference)
//
#include <hip/hip_runtime.h>
#include <hip/hip_cooperative_groups.h>
#include <hip/hip_bf16.h>
#include <math.h>
#include <stdint.h>

namespace cg = cooperative_groups;

// Problem constants (B=2, S=2048 -> T=4096 tokens)
#define TOKENS 4096
#define HDIM   768
#define FFDIM  1536
#define NEXP   8
#define N4W    (NEXP * FFDIM * HDIM / 4)   // float4 per weight tensor

typedef __attribute__((ext_vector_type(8))) short bf16x8;   // 8 bf16 = 4 VGPRs
typedef __attribute__((ext_vector_type(4))) float f32x4;    // MFMA accumulator
typedef __attribute__((ext_vector_type(4))) float fvec4;    // nt-load vector
typedef __attribute__((ext_vector_type(4))) unsigned short usvec4; // nt-store vector

// round-to-nearest-even f32 -> bf16 (bit pattern)
__device__ __forceinline__ unsigned short f2bf(float f) {
    union { float f; uint32_t u; } c; c.f = f;
    uint32_t u = c.u;
    uint32_t r = (u + 0x7FFFu + ((u >> 16) & 1u)) >> 16;
    return (unsigned short)r;
}

// async global->LDS, 16B per lane; LDS dest is wave-uniform base + lane*16
__device__ __forceinline__ void gload_lds16(const void* g, void* l) {
    __builtin_amdgcn_global_load_lds(
        (const __attribute__((address_space(1))) void*)g,
        (__attribute__((address_space(3))) void*)l, 16, 0, 0);
}

// cast one float4 -> ushort4 via clang ext_vector types (nt builtins reject
// HIP_vector_type — r10 lesson). NT load: weight source is a pure stream.
template<bool NTST>
__device__ __forceinline__ void cast4(const float* __restrict__ s,
                                      unsigned short* __restrict__ d, int i) {
    fvec4 v = __builtin_nontemporal_load((const fvec4*)s + i);
    usvec4 o;
    o.x = f2bf(v.x); o.y = f2bf(v.y); o.z = f2bf(v.z); o.w = f2bf(v.w);
    if constexpr (NTST) __builtin_nontemporal_store(o, (usvec4*)d + i);
    else                ((usvec4*)d)[i] = o;
}

// ---------------------------------------------------------------------------
// Per-expert routed-list scan: ONE 512-thread block handles expert e.
// Pass 1: count (no big register arrays — r11's eL[16]/gL[16] caching pushed
// VGPR to 128 and cost a block/CU). Pass 2: RELOAD tok_e/tok_g (L2-hot) and
// emit. Slot order == ascending global (t,k) — bit-identical to r8's lists.
__device__ void scan_expert(int e,
    const int* __restrict__ tok_e, const float* __restrict__ tok_g,
    int* __restrict__ counts, int* __restrict__ entries, float* __restrict__ gates,
    unsigned* wtot, unsigned* wbase)   // LDS scratch, 8 each
{
    int tid = threadIdx.x, lane = tid & 63, wid = tid >> 6;
    const int4* te4 = (const int4*)tok_e;
    const float4* tg4 = (const float4*)tok_g;
    unsigned cnt = 0;
#pragma unroll
    for (int b = 0; b < 4; b++) {
        int4 ev = te4[tid * 4 + b];
        cnt += (ev.x == e) + (ev.y == e) + (ev.z == e) + (ev.w == e);
    }
    unsigned il = cnt;
#pragma unroll
    for (int s = 1; s < 64; s <<= 1) {
        unsigned t1 = __shfl_up(il, s);
        if (lane >= s) il += t1;
    }
    if (lane == 63) wtot[wid] = il;
    __syncthreads();
    if (tid == 0) {
        unsigned r = 0;
#pragma unroll
        for (int i = 0; i < 8; i++) { unsigned a = wtot[i]; wbase[i] = r; r += a; }
        counts[e] = (int)r;
    }
    __syncthreads();
    unsigned slot = wbase[wid] + il - cnt;
#pragma unroll
    for (int b = 0; b < 4; b++) {
        int4 ev = te4[tid * 4 + b];
        float4 gv = tg4[tid * 4 + b];
        int ee[4] = {ev.x, ev.y, ev.z, ev.w};
        float gg[4] = {gv.x, gv.y, gv.z, gv.w};
#pragma unroll
        for (int j = 0; j < 4; j++) {
            if (ee[j] == e) {
                entries[e * TOKENS + slot] = tid * 16 + b * 4 + j;   // = t*2+k
                gates[e * TOKENS + slot]   = gg[j];
                slot++;
            }
        }
    }
}

// ---------------------------------------------------------------------------
// Routed GEMM phase (r8's proven kernels as a __device__ function; smem
// passed in, no early block exit — every block must reach the caller's
// grid.sync). BM=256, 8 waves (4x2).
//   !DBUF (GEMM1): TN=128, single-buffer drain-0 K-loop, 48KB of smem.
//   DBUF  (GEMM2): TN=64, T4 counted-vmcnt double-buffer (vmcnt(5), never 0
//   in-loop), 80KB of smem.
// LDS rows 128B = 8x16B segs, XOR swizzle seg^(row&7): 0 bank conflicts
// (verified r6). Geometry from counts[8]; bucket == expert.
template<int KD, int ND, int TN, int NCTP, bool IS_FC, bool DBUF>
__device__ void gemm_phase(unsigned short* smem,
    const unsigned short* __restrict__ Asrc,
    const unsigned short* __restrict__ Bsrc,    // [E][ND][KD] (B^T form)
    const int* __restrict__ counts,
    const int* __restrict__ entries,
    const float* __restrict__ gates,
    unsigned short* __restrict__ hmid,
    float* __restrict__ outp)
{
    constexpr int BM = 256;
    constexpr int AJ = TN / 32;        // col frags per wave (4 or 2)
    constexpr int CB = TN / 64;        // B staging calls per wave (2 or 1)
    constexpr int NV = 4 + CB;         // gload_lds per wave per stage
    int slots = (int)(gridDim.x >> 3);
    int bkt  = (int)(blockIdx.x & 7);  // bucket == expert
    int slot = (int)(blockIdx.x >> 3);

    int n_e = counts[bkt];
    int rts = (n_e + BM - 1) >> 8;
    int nfill = rts * NCTP;
    int ebase = 0;
#pragma unroll
    for (int e = 0; e < NEXP; e++) { int c = counts[e]; if (e < bkt) ebase += c; }
    const int* lst = entries + bkt * TOKENS;

    int tid = threadIdx.x;
    int w = tid >> 6;          // wave 0..7
    int l = tid & 63;          // lane
    int sg = l & 7;
    int lr8 = l >> 3;          // row-within-8 staged by this lane
    int lo = l & 15;
    int q  = l >> 4;
    int wr = w >> 1, wc = w & 1;   // 4x2 wave grid: 64 rows x TN/2 cols each

    unsigned short* sA0 = smem;
    unsigned short* sA1 = smem + BM * 64;                       // DBUF only
    unsigned short* sB0 = DBUF ? (smem + 2 * BM * 64) : (smem + BM * 64);
    unsigned short* sB1 = DBUF ? (smem + 2 * BM * 64 + TN * 64) : (smem + BM * 64);

    // fragment LDS offsets (item-independent)
    int aOff[4][2], bOff[AJ][2];
#pragma unroll
    for (int i = 0; i < 4; i++) {
        int m = wr * 64 + i * 16 + lo;
#pragma unroll
        for (int s = 0; s < 2; s++)
            aOff[i][s] = m * 64 + ((s * 4 + q) ^ (m & 7)) * 8;
    }
#pragma unroll
    for (int j = 0; j < AJ; j++) {
        int n = wc * (TN / 2) + j * 16 + lo;
#pragma unroll
        for (int s = 0; s < 2; s++)
            bOff[j][s] = n * 64 + ((s * 4 + q) ^ (n & 7)) * 8;
    }

    for (int p = slot; p < nfill; p += slots) {   // zero iters if beyond fill
        int ct   = p / rts;
        int r    = p - ct * rts;
        int row0 = r << 8;
        int n0 = ct * TN;

        // ---- staging addresses: rows are 128B (64 shorts), 8 segs of 16B.
        const unsigned short* Ag[4];
        int aLds[4];
#pragma unroll
        for (int c = 0; c < 4; c++) {
            int rr = w * 32 + c * 8 + lr8;       // tile row 0..255
            int gr = row0 + rr;
            int id = gr < n_e ? gr : n_e - 1;    // clamp (discarded in epilogue)
            size_t arow = IS_FC ? (size_t)(lst[id] >> 1) : (size_t)(ebase + id);
            Ag[c] = Asrc + arow * KD + (size_t)((sg ^ (rr & 7)) * 8);
            aLds[c] = (w * 32 + c * 8) * 64;     // wave-uniform chunk base
        }
        const unsigned short* Bg[CB];
        int bLds[CB];
#pragma unroll
        for (int c = 0; c < CB; c++) {
            int rr = w * (TN / 8) + c * 8 + lr8; // tile row 0..TN-1
            Bg[c] = Bsrc + ((size_t)bkt * ND + n0 + rr) * KD + (size_t)((sg ^ (rr & 7)) * 8);
            bLds[c] = (w * (TN / 8) + c * 8) * 64;
        }

        f32x4 acc[4][AJ];
#pragma unroll
        for (int i = 0; i < 4; i++)
#pragma unroll
            for (int j = 0; j < AJ; j++) acc[i][j] = (f32x4){0.f, 0.f, 0.f, 0.f};

        auto stage = [&](unsigned short* SA, unsigned short* SB, int k0) {
#pragma unroll
            for (int c = 0; c < 4; c++) gload_lds16(Ag[c] + k0, SA + aLds[c]);
#pragma unroll
            for (int c = 0; c < CB; c++) gload_lds16(Bg[c] + k0, SB + bLds[c]);
        };
        auto compute = [&](const unsigned short* SA, const unsigned short* SB) {
#pragma unroll
            for (int s = 0; s < 2; s++) {
                bf16x8 a[4], b[AJ];
#pragma unroll
                for (int i = 0; i < 4; i++) a[i] = *(const bf16x8*)(SA + aOff[i][s]);
#pragma unroll
                for (int j = 0; j < AJ; j++) b[j] = *(const bf16x8*)(SB + bOff[j][s]);
#pragma unroll
                for (int i = 0; i < 4; i++)
#pragma unroll
                    for (int j = 0; j < AJ; j++)
                        acc[i][j] = __builtin_amdgcn_mfma_f32_16x16x32_bf16(a[i], b[j], acc[i][j], 0, 0, 0);
            }
        };

        if constexpr (!DBUF) {
            // single-buffer, drain-0 __syncthreads loop (r5 proven, 51.2us)
            for (int k0 = 0; k0 < KD; k0 += 64) {
                stage(sA0, sB0, k0);
                __syncthreads();                // drains vmcnt (compiler-inserted)
                compute(sA0, sB0);
                __syncthreads();                // protect LDS before next staging
            }
        } else {
            // T4 counted-vmcnt double-buffer, raw barriers (r5 proven)
#define WAITN asm volatile("s_waitcnt vmcnt(%0)" :: "n"(NV) : "memory")
#define WAIT0 asm volatile("s_waitcnt vmcnt(0)" ::: "memory")
            stage(sA0, sB0, 0);
            for (int k0 = 0; k0 < KD; k0 += 128) {   // KD/128 = 12 iters
                stage(sA1, sB1, k0 + 64);
                WAITN;
                __builtin_amdgcn_s_barrier();
                __builtin_amdgcn_s_setprio(1);
                compute(sA0, sB0);
                __builtin_amdgcn_s_setprio(0);
                __builtin_amdgcn_s_barrier();
                if (k0 + 128 < KD) {
                    stage(sA0, sB0, k0 + 128);
                    WAITN;
                } else {
                    WAIT0;
                }
                __builtin_amdgcn_s_barrier();
                __builtin_amdgcn_s_setprio(1);
                compute(sA1, sB1);
                __builtin_amdgcn_s_setprio(0);
                __builtin_amdgcn_s_barrier();
            }
#undef WAITN
#undef WAIT0
        }

        // ---- epilogue (D: col=lo, row=q*4+rr)
#pragma unroll
        for (int i = 0; i < 4; i++) {
            int rowB = row0 + wr * 64 + i * 16 + q * 4;
#pragma unroll
            for (int rr = 0; rr < 4; rr++) {
                int orow = rowB + rr;
                if (orow < n_e) {
                    if (IS_FC) {
                        size_t hrow = (size_t)(ebase + orow);
#pragma unroll
                        for (int j = 0; j < AJ; j++) {
                            float v = acc[i][j][rr];
                            v = 0.5f * v * (1.f + erff(v * 0.70710678118654752f));  // exact gelu
                            hmid[hrow * ND + n0 + wc * (TN / 2) + j * 16 + lo] = f2bf(v);
                        }
                    } else {
                        int token = lst[orow] >> 1;
                        float g = gates[bkt * TOKENS + orow];
#pragma unroll
                        for (int j = 0; j < AJ; j++) {
                            atomicAdd(&outp[(size_t)token * ND + n0 + wc * (TN / 2) + j * 16 + lo],
                                      acc[i][j][rr] * g);
                        }
                    }
                }
            }
        }
    }
}

// ---------------------------------------------------------------------------
// SINGLE cooperative kernel (r12): all 4 phases, grid.sync between — the 3
// launch boundaries (~10-15us each by r8 accounting) vanish. 512 blocks x
// 512 threads, __launch_bounds__(512,4) caps VGPR at 128; 80KB smem -> 2
// blk/CU -> exactly 512 co-resident (cooperative launch validates). All
// phase loops are grid-stride, so a smaller grid (occupancy fallback) stays
// correct. No spin loops anywhere — no hang mode.
struct MoeP {
    const float *x, *gw, *wfc, *wproj;
    float *outp, *logits;
    int *counts, *entries;
    float *gates;
    int *tok_e; float *tok_g;
    unsigned short *x_bf, *wfc_bf, *wpj_bf, *hmid;
};

__global__ __launch_bounds__(512, 4) void moe_fused(MoeP P)
{
    __shared__ __align__(16) unsigned short smem[40960];   // 80KB, phase-aliased
    cg::grid_group grid = cg::this_grid();
    int tid = threadIdx.x, bid = (int)blockIdx.x, nb = (int)gridDim.x;

    // ==== phase A: outp zero + gating + wfc cast ====
    float4 zz = make_float4(0.f, 0.f, 0.f, 0.f);
    for (int i = bid * 512 + tid; i < TOKENS * HDIM / 4; i += nb * 512)
        ((float4*)P.outp)[i] = zz;

    {
        int lane = tid & 63, w = tid >> 6;
        for (int tg = bid; tg < TOKENS / 8; tg += nb) {
            int t = tg * 8 + w;                                   // 1 wave / token
            const float4* xt = (const float4*)(P.x + (size_t)t * HDIM);  // 192 f4
            const float4* gw4 = (const float4*)P.gw;              // [E][192]
            ushort4* xbt = (ushort4*)(P.x_bf + (size_t)t * HDIM);
            float acc[NEXP];
#pragma unroll
            for (int e = 0; e < NEXP; e++) acc[e] = 0.f;
#pragma unroll
            for (int it = 0; it < 3; it++) {
                int i = lane + it * 64;
                float4 xv = xt[i];
                ushort4 o;
                o.x = f2bf(xv.x); o.y = f2bf(xv.y); o.z = f2bf(xv.z); o.w = f2bf(xv.w);
                xbt[i] = o;
#pragma unroll
                for (int e = 0; e < NEXP; e++) {
                    float4 wv = gw4[e * 192 + i];
                    acc[e] += xv.x * wv.x + xv.y * wv.y + xv.z * wv.z + xv.w * wv.w;
                }
            }
#pragma unroll
            for (int e = 0; e < NEXP; e++) {
#pragma unroll
                for (int off = 32; off > 0; off >>= 1)
                    acc[e] += __shfl_xor(acc[e], off);
            }
            if (lane == 0) {
                float4 l0 = make_float4(acc[0], acc[1], acc[2], acc[3]);
                float4 l1 = make_float4(acc[4], acc[5], acc[6], acc[7]);
                float4* lp = (float4*)(P.logits + (size_t)t * NEXP);
                lp[0] = l0; lp[1] = l1;
                int i0 = 0; float v0 = acc[0];
#pragma unroll
                for (int e = 1; e < NEXP; e++) if (acc[e] > v0) { v0 = acc[e]; i0 = e; }
                int i1 = -1; float v1 = -3.4e38f;
#pragma unroll
                for (int e = 0; e < NEXP; e++) if (e != i0 && acc[e] > v1) { v1 = acc[e]; i1 = e; }
                float g0 = 1.f / (1.f + expf(v1 - v0));   // softmax over top-2
                P.tok_e[t * 2] = i0; P.tok_e[t * 2 + 1] = i1;
                P.tok_g[t * 2] = g0; P.tok_g[t * 2 + 1] = 1.f - g0;
            }
        }
    }
    for (int i = bid * 512 + tid; i < N4W; i += nb * 512)
        cast4<false>(P.wfc, P.wfc_bf, i);

    __threadfence();
    grid.sync();

    // ==== phase B: 8-block parallel routed-list scan (r8-proven logic) ====
    if (bid < NEXP)
        scan_expert(bid, P.tok_e, P.tok_g, P.counts, P.entries, P.gates,
                    (unsigned*)smem, (unsigned*)smem + 8);
    __threadfence();
    grid.sync();

    // ==== phase C: GEMM1 (x_bf @ wfc^T -> gelu -> hmid) + wproj cast ====
    gemm_phase<HDIM, FFDIM, 128, FFDIM / 128, true, false>(
        smem, P.x_bf, P.wfc_bf, P.counts, P.entries, P.gates, P.hmid, P.outp);
    for (int i = bid * 512 + tid; i < N4W; i += nb * 512)
        cast4<true>(P.wproj, P.wpj_bf, i);
    __threadfence();
    grid.sync();

    // ==== phase D: GEMM2 (hmid @ wproj^T, gated atomic combine) ====
    gemm_phase<FFDIM, HDIM, 64, HDIM / 64, false, true>(
        smem, P.hmid, P.wpj_bf, P.counts, P.entries, P.gates, P.hmid, P.outp);
}

// ---------------------------------------------------------------------------
extern "C" void kernel_launch(void* const* d_in, const int* in_sizes, int n_in,
                              void* d_out, int out_size, void* d_ws, size_t ws_size,
                              hipStream_t stream) {
    const float* x     = (const float*)d_in[0];   // [T, H]
    const float* gw    = (const float*)d_in[1];   // [E, H]
    const float* wfc   = (const float*)d_in[2];   // [E, FF, H]
    const float* wproj = (const float*)d_in[3];   // [E, H, FF]
    float* outp   = (float*)d_out;                       // [T*H]
    float* logits = outp + (size_t)TOKENS * HDIM;        // [T*E]

    char* ws = (char*)d_ws;
    int*   counts  = (int*)ws;                            // 8 ints
    size_t off = 256;
    int*   entries = (int*)(ws + off);                    // [E][T]
    float* gates   = (float*)(ws + off + NEXP * TOKENS * 4);
    off += 2ull * NEXP * TOKENS * 4;
    int*   tok_e   = (int*)(ws + off);   off += (size_t)TOKENS * 2 * 4;
    float* tok_g   = (float*)(ws + off); off += (size_t)TOKENS * 2 * 4;
    unsigned short* x_bf   = (unsigned short*)(ws + off); off += (size_t)TOKENS * HDIM * 2;
    unsigned short* wfc_bf = (unsigned short*)(ws + off); off += (size_t)NEXP * FFDIM * HDIM * 2;
    unsigned short* wpj_bf = (unsigned short*)(ws + off); off += (size_t)NEXP * HDIM * FFDIM * 2;
    unsigned short* hmid   = (unsigned short*)(ws + off);        // [2T][FF] bf16

    MoeP P;
    P.x = x; P.gw = gw; P.wfc = wfc; P.wproj = wproj;
    P.outp = outp; P.logits = logits;
    P.counts = counts; P.entries = entries; P.gates = gates;
    P.tok_e = tok_e; P.tok_g = tok_g;
    P.x_bf = x_bf; P.wfc_bf = wfc_bf; P.wpj_bf = wpj_bf; P.hmid = hmid;

    int maxB = 2;
    (void)hipOccupancyMaxActiveBlocksPerMultiprocessor(&maxB, moe_fused, 512, 0);
    int grid = maxB * 256;
    if (grid > 512) grid = 512;
    if (grid < 8)   grid = 256;    // paranoia clamp; 8 blocks minimum for scan

    void* args[] = { (void*)&P };
    (void)hipLaunchCooperativeKernel((const void*)moe_fused, dim3(grid), dim3(512),
                                     args, 0, stream);
}

// Round 13
// 228.791 us; speedup vs baseline: 2.3160x; 2.3160x over previous
//
#include <hip/hip_runtime.h>
#include <hip/hip_bf16.h>
#include <math.h>
#include <stdint.h>

// Problem constants (B=2, S=2048 -> T=4096 tokens)
#define TOKENS 4096
#define HDIM   768
#define FFDIM  1536
#define NEXP   8

typedef __attribute__((ext_vector_type(8))) short bf16x8;   // 8 bf16 = 4 VGPRs
typedef __attribute__((ext_vector_type(4))) float f32x4;    // MFMA accumulator
typedef __attribute__((ext_vector_type(4))) float fvec4;    // nt-load vector
typedef __attribute__((ext_vector_type(4))) unsigned short usvec4; // nt-store vector

// round-to-nearest-even f32 -> bf16 (bit pattern)
__device__ __forceinline__ unsigned short f2bf(float f) {
    union { float f; uint32_t u; } c; c.f = f;
    uint32_t u = c.u;
    uint32_t r = (u + 0x7FFFu + ((u >> 16) & 1u)) >> 16;
    return (unsigned short)r;
}

// async global->LDS, 16B per lane; LDS dest is wave-uniform base + lane*16
__device__ __forceinline__ void gload_lds16(const void* g, void* l) {
    __builtin_amdgcn_global_load_lds(
        (const __attribute__((address_space(1))) void*)g,
        (__attribute__((address_space(3))) void*)l, 16, 0, 0);
}

// cast one float4 -> ushort4 via clang ext_vector types (nt builtins reject
// HIP_vector_type — r10 lesson). NT LOAD always: the f32 weight source is a
// pure stream, never reused — keep it out of L2. NT STORE only for wpj_bf:
// it is written WHILE GEMM1 runs and read only next dispatch; a normal store
// would evict GEMM1's B panels / x_bf gather set from L2 (r8's +8.3us
// cast-arm overhead is this pollution).
template<bool NTST>
__device__ __forceinline__ void cast4(const float* __restrict__ s,
                                      unsigned short* __restrict__ d, int i) {
    fvec4 v = __builtin_nontemporal_load((const fvec4*)s + i);
    usvec4 o;
    o.x = f2bf(v.x); o.y = f2bf(v.y); o.z = f2bf(v.z); o.w = f2bf(v.w);
    if constexpr (NTST) __builtin_nontemporal_store(o, (usvec4*)d + i);
    else                ((usvec4*)d)[i] = o;
}

// ---------------------------------------------------------------------------
// Gating (r8 structure): one wave per token (4 tokens / 256-thread block).
// fp32 logits (checked output!), top-2 softmax, NO atomics (r2: contended
// atomics serialized to 102us). Fused: bf16 cast of x, zeroing of outp.
__global__ __launch_bounds__(256) void gating(
    const float* __restrict__ x, const float* __restrict__ gw,
    float* __restrict__ logits,
    int* __restrict__ tok_e, float* __restrict__ tok_g,
    unsigned short* __restrict__ x_bf, float* __restrict__ outp)
{
    // zero outp: 786432 float4 over 1024 blocks = 3 per thread
    float4 zz = make_float4(0.f, 0.f, 0.f, 0.f);
#pragma unroll
    for (int j = 0; j < 3; j++)
        ((float4*)outp)[blockIdx.x * 768 + j * 256 + threadIdx.x] = zz;

    int t = blockIdx.x * 4 + (threadIdx.x >> 6);
    int lane = threadIdx.x & 63;
    const float4* xt = (const float4*)(x + (size_t)t * HDIM);   // 192 float4/token
    const float4* gw4 = (const float4*)gw;                      // [E][192]
    ushort4* xbt = (ushort4*)(x_bf + (size_t)t * HDIM);
    float acc[NEXP];
#pragma unroll
    for (int e = 0; e < NEXP; e++) acc[e] = 0.f;
#pragma unroll
    for (int it = 0; it < 3; it++) {
        int i = lane + it * 64;
        float4 xv = xt[i];
        ushort4 o;
        o.x = f2bf(xv.x); o.y = f2bf(xv.y); o.z = f2bf(xv.z); o.w = f2bf(xv.w);
        xbt[i] = o;
#pragma unroll
        for (int e = 0; e < NEXP; e++) {
            float4 wv = gw4[e * 192 + i];
            acc[e] += xv.x * wv.x + xv.y * wv.y + xv.z * wv.z + xv.w * wv.w;
        }
    }
#pragma unroll
    for (int e = 0; e < NEXP; e++) {
#pragma unroll
        for (int off = 32; off > 0; off >>= 1)
            acc[e] += __shfl_xor(acc[e], off);
    }
    if (lane == 0) {
        float4 l0 = make_float4(acc[0], acc[1], acc[2], acc[3]);
        float4 l1 = make_float4(acc[4], acc[5], acc[6], acc[7]);
        float4* lp = (float4*)(logits + (size_t)t * NEXP);
        lp[0] = l0; lp[1] = l1;
        int i0 = 0; float v0 = acc[0];
#pragma unroll
        for (int e = 1; e < NEXP; e++) if (acc[e] > v0) { v0 = acc[e]; i0 = e; }
        int i1 = -1; float v1 = -3.4e38f;
#pragma unroll
        for (int e = 0; e < NEXP; e++) if (e != i0 && acc[e] > v1) { v1 = acc[e]; i1 = e; }
        float g0 = 1.f / (1.f + expf(v1 - v0));   // softmax over top-2 (v0 >= v1)
        tok_e[t * 2] = i0; tok_e[t * 2 + 1] = i1;
        tok_g[t * 2] = g0; tok_g[t * 2 + 1] = 1.f - g0;
    }
}

// ---------------------------------------------------------------------------
// r8: build lists with 8 PARALLEL blocks (one expert each) + wfc cast arm.
// The single-block version issued ~16k scattered stores from ONE CU; per-
// expert blocks cut that 8x and keep slot order (token order within expert)
// BIT-IDENTICAL. Blocks 8..1031 stream-cast wfc -> bf16 (needed first by
// GEMM1, next dispatch) with NT loads.
__global__ __launch_bounds__(1024) void build_cast(
    const int* __restrict__ tok_e, const float* __restrict__ tok_g,
    int* __restrict__ counts,
    int* __restrict__ entries, float* __restrict__ gates,
    const float* __restrict__ wfc, unsigned short* __restrict__ wfc_bf, int n4)
{
    if (blockIdx.x >= 8) {
        // ---- wfc cast arm (1024 blocks x 1024 thr): nt loads
        int stride = 1024 * 1024;
        for (int i = (int)(blockIdx.x - 8) * 1024 + threadIdx.x; i < n4; i += stride)
            cast4<false>(wfc, wfc_bf, i);
        return;
    }
    // ---- scan arm: this block owns expert e
    int e = blockIdx.x;
    __shared__ unsigned wtot[16], wbase[16];
    int tid = threadIdx.x;
    int lane = tid & 63, wid = tid >> 6;

    int eL[8]; float gL[8];
    int4 ea = ((const int4*)tok_e)[tid * 2];
    int4 eb = ((const int4*)tok_e)[tid * 2 + 1];
    float4 ga = ((const float4*)tok_g)[tid * 2];
    float4 gb = ((const float4*)tok_g)[tid * 2 + 1];
    eL[0] = ea.x; eL[1] = ea.y; eL[2] = ea.z; eL[3] = ea.w;
    eL[4] = eb.x; eL[5] = eb.y; eL[6] = eb.z; eL[7] = eb.w;
    gL[0] = ga.x; gL[1] = ga.y; gL[2] = ga.z; gL[3] = ga.w;
    gL[4] = gb.x; gL[5] = gb.y; gL[6] = gb.z; gL[7] = gb.w;

    unsigned m = 0, cnt = 0;
#pragma unroll
    for (int j = 0; j < 8; j++)
        if (eL[j] == e) { m |= 1u << j; cnt++; }

    unsigned il = cnt;                       // inclusive wave scan
#pragma unroll
    for (int s = 1; s < 64; s <<= 1) {
        unsigned t1 = __shfl_up(il, s);
        if (lane >= s) il += t1;
    }
    if (lane == 63) wtot[wid] = il;
    __syncthreads();
    if (tid == 0) {
        unsigned r = 0;
#pragma unroll
        for (int i = 0; i < 16; i++) { unsigned a = wtot[i]; wbase[i] = r; r += a; }
        counts[e] = (int)r;
    }
    __syncthreads();
    unsigned slot = wbase[wid] + (il - cnt); // exclusive thread prefix
#pragma unroll
    for (int j = 0; j < 8; j++) {
        if (m & (1u << j)) {
            entries[e * TOKENS + slot] = tid * 8 + j;   // = t*2+k
            gates[e * TOKENS + slot]   = gL[j];
            slot++;
        }
    }
}

// ---------------------------------------------------------------------------
// Routed GEMM, r13 = r8's proven configs + nt-cast (single variable).
// BM=256, 8 waves (4x2).
//   GEMM1 (IS_FC, DBUF=false): TN=128, single-buffer drain-0 K-loop,
//     48KB LDS -> 3 blk/CU; grid 768 GEMM blocks (~430 items, single span)
//     + 512 CAST blocks that stream wproj -> bf16 with NT load + NT store
//     (needed only by GEMM2, the NEXT dispatch — stream order guarantees
//     completion). r5-proven 51.2us + reduced cast contention.
//   GEMM2 (DBUF=true): TN=64, T4 counted-vmcnt double-buffer (raw s_barrier
//     + s_waitcnt vmcnt(5), never 0 in-loop), 80KB -> 2 blk/CU. r5-proven.
// LDS rows 128B = 8x16B segs, XOR swizzle seg^(row&7): ds_read_b128
// bank-uniform, 0 conflicts (verified r6). Geometry from counts[8];
// bucket == expert (XCD-affine under round-robin dispatch).
template<int KD, int ND, int TN, int NCTP, int GG, bool IS_FC, bool DBUF>
__global__ __launch_bounds__(512) void moe_gemm(
    const unsigned short* __restrict__ Asrc,
    const unsigned short* __restrict__ Bsrc,    // [E][ND][KD] (B^T form)
    const int* __restrict__ counts,
    const int* __restrict__ entries,
    const float* __restrict__ gates,
    unsigned short* __restrict__ hmid,
    float* __restrict__ outp,
    const float* __restrict__ castS, unsigned short* __restrict__ castD, int castN4)
{
    if constexpr (IS_FC) {
        if (blockIdx.x >= GG) {     // ---- wproj cast arm (512 blocks x 512 thr)
            int stride = 512 * 512;
            for (int i = (int)(blockIdx.x - GG) * 512 + threadIdx.x; i < castN4; i += stride)
                cast4<true>(castS, castD, i);
            return;
        }
    }
    constexpr int BM = 256;
    constexpr int SLOTS = GG / 8;
    constexpr int AJ = TN / 32;        // col frags per wave (4 or 2)
    constexpr int CB = TN / 64;        // B staging calls per wave (2 or 1)
    constexpr int NV = 4 + CB;         // gload_lds per wave per stage
    int bkt  = blockIdx.x & 7;         // bucket == expert
    int slot = blockIdx.x >> 3;        // 0..SLOTS-1

    // early exit needs only this bucket's count (exiters vacate for casts)
    int n_e = counts[bkt];
    int rts = (n_e + BM - 1) >> 8;
    int nfill = rts * NCTP;
    if (slot >= nfill) return;
    int ebase = 0;
#pragma unroll
    for (int e = 0; e < NEXP; e++) { int c = counts[e]; if (e < bkt) ebase += c; }
    const int* lst = entries + bkt * TOKENS;

    int tid = threadIdx.x;
    int w = tid >> 6;          // wave 0..7
    int l = tid & 63;          // lane
    int sg = l & 7;
    int lr8 = l >> 3;          // row-within-8 staged by this lane
    int lo = l & 15;
    int q  = l >> 4;
    int wr = w >> 1, wc = w & 1;   // 4x2 wave grid: 64 rows x TN/2 cols each

    __shared__ __align__(16) unsigned short sA[(DBUF ? 2 : 1) * BM * 64];
    __shared__ __align__(16) unsigned short sB[(DBUF ? 2 : 1) * TN * 64];
    unsigned short* sA0 = sA;
    unsigned short* sA1 = sA + BM * 64;   // compile-time offsets (static alias)
    unsigned short* sB0 = sB;
    unsigned short* sB1 = sB + TN * 64;

    // fragment LDS offsets (item-independent)
    int aOff[4][2], bOff[AJ][2];
#pragma unroll
    for (int i = 0; i < 4; i++) {
        int m = wr * 64 + i * 16 + lo;
#pragma unroll
        for (int s = 0; s < 2; s++)
            aOff[i][s] = m * 64 + ((s * 4 + q) ^ (m & 7)) * 8;
    }
#pragma unroll
    for (int j = 0; j < AJ; j++) {
        int n = wc * (TN / 2) + j * 16 + lo;
#pragma unroll
        for (int s = 0; s < 2; s++)
            bOff[j][s] = n * 64 + ((s * 4 + q) ^ (n & 7)) * 8;
    }

    for (int p = slot; p < nfill; p += SLOTS) {   // backstop stride; 1 iter typical
        int ct   = p / rts;
        int r    = p - ct * rts;
        int row0 = r << 8;
        int n0 = ct * TN;

        // ---- staging addresses: rows are 128B (64 shorts), 8 segs of 16B.
        // A call covers 8 rows (64 lanes x 16B = 1KB). Global K-seg for
        // (row rr, LDS seg sg) is sg ^ (rr&7). Wave w stages A rows
        // [w*32, w*32+32) (4 calls) and B rows [w*(TN/8), ...) (CB calls).
        const unsigned short* Ag[4];
        int aLds[4];
#pragma unroll
        for (int c = 0; c < 4; c++) {
            int rr = w * 32 + c * 8 + lr8;       // tile row 0..255
            int gr = row0 + rr;
            int id = gr < n_e ? gr : n_e - 1;    // clamp (discarded in epilogue)
            size_t arow = IS_FC ? (size_t)(lst[id] >> 1) : (size_t)(ebase + id);
            Ag[c] = Asrc + arow * KD + (size_t)((sg ^ (rr & 7)) * 8);
            aLds[c] = (w * 32 + c * 8) * 64;     // wave-uniform chunk base
        }
        const unsigned short* Bg[CB];
        int bLds[CB];
#pragma unroll
        for (int c = 0; c < CB; c++) {
            int rr = w * (TN / 8) + c * 8 + lr8; // tile row 0..TN-1
            Bg[c] = Bsrc + ((size_t)bkt * ND + n0 + rr) * KD + (size_t)((sg ^ (rr & 7)) * 8);
            bLds[c] = (w * (TN / 8) + c * 8) * 64;
        }

        f32x4 acc[4][AJ];
#pragma unroll
        for (int i = 0; i < 4; i++)
#pragma unroll
            for (int j = 0; j < AJ; j++) acc[i][j] = (f32x4){0.f, 0.f, 0.f, 0.f};

        auto stage = [&](unsigned short* SA, unsigned short* SB, int k0) {
#pragma unroll
            for (int c = 0; c < 4; c++) gload_lds16(Ag[c] + k0, SA + aLds[c]);
#pragma unroll
            for (int c = 0; c < CB; c++) gload_lds16(Bg[c] + k0, SB + bLds[c]);
        };
        auto compute = [&](const unsigned short* SA, const unsigned short* SB) {
#pragma unroll
            for (int s = 0; s < 2; s++) {
                bf16x8 a[4], b[AJ];
#pragma unroll
                for (int i = 0; i < 4; i++) a[i] = *(const bf16x8*)(SA + aOff[i][s]);
#pragma unroll
                for (int j = 0; j < AJ; j++) b[j] = *(const bf16x8*)(SB + bOff[j][s]);
#pragma unroll
                for (int i = 0; i < 4; i++)
#pragma unroll
                    for (int j = 0; j < AJ; j++)
                        acc[i][j] = __builtin_amdgcn_mfma_f32_16x16x32_bf16(a[i], b[j], acc[i][j], 0, 0, 0);
            }
        };

        if constexpr (!DBUF) {
            // single-buffer, drain-0 __syncthreads loop (r5 control, 51.2us)
            for (int k0 = 0; k0 < KD; k0 += 64) {
                stage(sA0, sB0, k0);
                __syncthreads();                // drains vmcnt (compiler-inserted)
                compute(sA0, sB0);
                __syncthreads();                // protect LDS before next staging
            }
        } else {
            // T4 counted-vmcnt double-buffer, raw barriers; vmcnt(NV) retires
            // the older buffer's loads while the newest NV stay in flight.
#define WAITN asm volatile("s_waitcnt vmcnt(%0)" :: "n"(NV) : "memory")
#define WAIT0 asm volatile("s_waitcnt vmcnt(0)" ::: "memory")
            stage(sA0, sB0, 0);
            for (int k0 = 0; k0 < KD; k0 += 128) {   // KD/128 = 12 iters
                stage(sA1, sB1, k0 + 64);
                WAITN;
                __builtin_amdgcn_s_barrier();
                __builtin_amdgcn_s_setprio(1);
                compute(sA0, sB0);
                __builtin_amdgcn_s_setprio(0);
                __builtin_amdgcn_s_barrier();
                if (k0 + 128 < KD) {
                    stage(sA0, sB0, k0 + 128);
                    WAITN;
                } else {
                    WAIT0;
                }
                __builtin_amdgcn_s_barrier();
                __builtin_amdgcn_s_setprio(1);
                compute(sA1, sB1);
                __builtin_amdgcn_s_setprio(0);
                __builtin_amdgcn_s_barrier();
            }
#undef WAITN
#undef WAIT0
        }

        // ---- epilogue (D: col=lo, row=q*4+rr)
#pragma unroll
        for (int i = 0; i < 4; i++) {
            int rowB = row0 + wr * 64 + i * 16 + q * 4;
#pragma unroll
            for (int rr = 0; rr < 4; rr++) {
                int orow = rowB + rr;
                if (orow < n_e) {
                    if (IS_FC) {
                        size_t hrow = (size_t)(ebase + orow);
#pragma unroll
                        for (int j = 0; j < AJ; j++) {
                            float v = acc[i][j][rr];
                            v = 0.5f * v * (1.f + erff(v * 0.70710678118654752f));  // exact gelu
                            hmid[hrow * ND + n0 + wc * (TN / 2) + j * 16 + lo] = f2bf(v);
                        }
                    } else {
                        int token = lst[orow] >> 1;
                        float g = gates[bkt * TOKENS + orow];
#pragma unroll
                        for (int j = 0; j < AJ; j++) {
                            atomicAdd(&outp[(size_t)token * ND + n0 + wc * (TN / 2) + j * 16 + lo],
                                      acc[i][j][rr] * g);
                        }
                    }
                }
            }
        }
    }
}

// ---------------------------------------------------------------------------
extern "C" void kernel_launch(void* const* d_in, const int* in_sizes, int n_in,
                              void* d_out, int out_size, void* d_ws, size_t ws_size,
                              hipStream_t stream) {
    const float* x     = (const float*)d_in[0];   // [T, H]
    const float* gw    = (const float*)d_in[1];   // [E, H]
    const float* wfc   = (const float*)d_in[2];   // [E, FF, H]
    const float* wproj = (const float*)d_in[3];   // [E, H, FF]
    float* outp   = (float*)d_out;                       // [T*H]
    float* logits = outp + (size_t)TOKENS * HDIM;        // [T*E]

    char* ws = (char*)d_ws;
    int*   counts  = (int*)ws;                            // 8 ints
    size_t off = 256;
    int*   entries = (int*)(ws + off);                    // [E][T]
    float* gates   = (float*)(ws + off + NEXP * TOKENS * 4);
    off += 2ull * NEXP * TOKENS * 4;
    int*   tok_e   = (int*)(ws + off);   off += (size_t)TOKENS * 2 * 4;
    float* tok_g   = (float*)(ws + off); off += (size_t)TOKENS * 2 * 4;
    unsigned short* x_bf   = (unsigned short*)(ws + off); off += (size_t)TOKENS * HDIM * 2;
    unsigned short* wfc_bf = (unsigned short*)(ws + off); off += (size_t)NEXP * FFDIM * HDIM * 2;
    unsigned short* wpj_bf = (unsigned short*)(ws + off); off += (size_t)NEXP * HDIM * FFDIM * 2;
    unsigned short* hmid   = (unsigned short*)(ws + off);        // [2T][FF] bf16, slot-compacted

    gating<<<TOKENS / 4, 256, 0, stream>>>(x, gw, logits, tok_e, tok_g, x_bf, outp);
    build_cast<<<8 + 1024, 1024, 0, stream>>>(tok_e, tok_g, counts, entries, gates,
                                              wfc, wfc_bf, NEXP * FFDIM * HDIM / 4);
    moe_gemm<HDIM, FFDIM, 128, FFDIM / 128, 768, true,  false>
        <<<768 + 512, 512, 0, stream>>>(
        x_bf, wfc_bf, counts, entries, gates, hmid, outp,
        wproj, wpj_bf, NEXP * HDIM * FFDIM / 4);
    moe_gemm<FFDIM, HDIM, 64,  HDIM / 64,   512, false, true >
        <<<512, 512, 0, stream>>>(
        hmid, wpj_bf, counts, entries, gates, hmid, outp,
        nullptr, nullptr, 0);
}